// Round 13
// baseline (784.899 us; speedup 1.0000x reference)
//
#include <hip/hip_runtime.h>
#include <stdint.h>

// SmallMLP_INR: fused 6-layer MLP (2->256->256x4->1, ReLU) over 524288 points.
// Split-bf16 MFMA (x = hi + lo, truncate split): Y = Xh*Wh + Xh*Wl + Xl*Wh in fp32.
// Operand-swapped: Yt = Wt * Xt (weights = A-frag from global, acts = B-frag in LDS).
// R13 = R12 with the wave work-split changed (2ft x 4pt) -> (4ft x 2pt):
// wave owns 64 features x 32 points (8 waves = 4 feature-groups x 2 point-halves).
// Per-ks per-wave: LDS B-frag reads 8 -> 4 (block LDS read traffic HALVES,
// port occupancy ~56% -> ~28%), global A-frag loads 4 -> 8 (L2 weight traffic
// doubles to ~30 TB/s, under the ~34.5 ceiling; W is L1/L2 resident).
// MFMA count, packing, swizzle, layer1, epilogue pattern unchanged.
// VGPR discipline (R8/R11): prefetch ONLY wh one ks ahead; wl JIT at burst
// start (first used at MFMA #17, ~310 cyc cover). ~113 VGPR < 128 cliff.
// Kept: lgkm-only barriers + epilogue VALU hoist (R12), fused L6, setprio,
// launch_bounds(512,4), 16x16x32 shape, MT=64.

#define WIDTH 256
#define MT 64

typedef short short8 __attribute__((ext_vector_type(8)));
typedef float float4v __attribute__((ext_vector_type(4)));
typedef unsigned int uint2v __attribute__((ext_vector_type(2)));

// lgkm-only barrier: LDS ordering without draining global (vmcnt) prefetch.
__device__ __forceinline__ void barrier_lgkm() {
    asm volatile("s_waitcnt lgkmcnt(0)" ::: "memory");
    __builtin_amdgcn_s_barrier();
    __builtin_amdgcn_sched_barrier(0);
}

// truncate-split f32 -> bf16 hi + bf16 lo (lo also truncated; total ~16-17 bits)
__device__ __forceinline__ void split_bf(float f, unsigned short &hi, unsigned short &lo) {
    union { float f; uint32_t u; } a; a.f = f;
    hi = (unsigned short)(a.u >> 16);
    union { uint32_t u; float f; } h; h.u = a.u & 0xffff0000u;
    union { float f; uint32_t u; } d; d.f = f - h.f;   // exact (Sterbenz)
    lo = (unsigned short)(d.u >> 16);
}

// pack hi(bf16) of two f32 into one u32 via v_perm_b32: D = {a.b2,a.b3,b.b2,b.b3}
__device__ __forceinline__ uint32_t phi2(float a, float b) {
    return __builtin_amdgcn_perm(__float_as_uint(b), __float_as_uint(a), 0x07060302u);
}
// pack lo(bf16) of two f32: residual after hi-truncation, then perm-pack
__device__ __forceinline__ uint32_t plo2(float a, float b) {
    float da = a - __uint_as_float(__float_as_uint(a) & 0xffff0000u);
    float db = b - __uint_as_float(__float_as_uint(b) & 0xffff0000u);
    return __builtin_amdgcn_perm(__float_as_uint(db), __float_as_uint(da), 0x07060302u);
}

// LDS activation addressing: X[m][n], row stride 256 ushorts, 16B-chunk index
// XOR-swizzled by (m&7) -> bank-minimal MFMA B-frag reads without padding.
__device__ __forceinline__ int xaddr(int m, int n) {
    int c = n >> 3;
    return m * 256 + (((c ^ (m & 7)) << 3) | (n & 7));
}

// Pack W2..W5 (256x256, row-major [k][n]) into MFMA fragment order:
// [l][ct(16)][ks(8)][lane(64)][j(8)], n = 16*ct + (lane&15), k = 32*ks + 8*(lane>>4) + j.
__global__ void prep_weights(const float* __restrict__ W2, const float* __restrict__ W3,
                             const float* __restrict__ W4, const float* __restrict__ W5,
                             unsigned short* __restrict__ whi, unsigned short* __restrict__ wlo) {
    int tid = blockIdx.x * 256 + threadIdx.x;   // 4*65536 total
    int l = tid >> 16;
    int e = tid & 65535;
    int j = e & 7;
    int lane = (e >> 3) & 63;
    int ks = (e >> 9) & 7;
    int ct = (e >> 12) & 15;
    int n = ct * 16 + (lane & 15);
    int k = ks * 32 + (lane >> 4) * 8 + j;
    const float* W = (l == 0) ? W2 : (l == 1) ? W3 : (l == 2) ? W4 : W5;
    float w = W[k * 256 + n];
    unsigned short hi, lo;
    split_bf(w, hi, lo);
    whi[tid] = hi;
    wlo[tid] = lo;
}

// weight hi A-frag load: ct = 4*wvf + ft (wave owns 64 consecutive features)
#define LOADWH(WH, L, KS)                                                      \
    do {                                                                       \
        _Pragma("unroll")                                                      \
        for (int _ft = 0; _ft < 4; ++_ft) {                                    \
            const int _idx = ((((L) * 16) + (4 * wvf + _ft)) * 8 + (KS)) * 512 \
                             + lane * 8;                                       \
            WH[_ft] = *(const short8*)(whi + _idx);                            \
        }                                                                      \
    } while (0)

// weight lo A-frag load (JIT: first used at MFMA #17 of the burst)
#define LOADWL(WL, L, KS)                                                      \
    do {                                                                       \
        _Pragma("unroll")                                                      \
        for (int _ft = 0; _ft < 4; ++_ft) {                                    \
            const int _idx = ((((L) * 16) + (4 * wvf + _ft)) * 8 + (KS)) * 512 \
                             + lane * 8;                                       \
            WL[_ft] = *(const short8*)(wlo + _idx);                            \
        }                                                                      \
    } while (0)

__global__ __launch_bounds__(512, 4) void mlp_fused(
    const float* __restrict__ coords,
    const float* __restrict__ W1, const float* __restrict__ b1,
    const float* __restrict__ b2, const float* __restrict__ b3,
    const float* __restrict__ b4, const float* __restrict__ b5,
    const float* __restrict__ W6, const float* __restrict__ b6,
    const unsigned short* __restrict__ whi, const unsigned short* __restrict__ wlo,
    float* __restrict__ out)
{
    __shared__ unsigned short Xhi[MT * 256];   // 32 KB
    __shared__ unsigned short Xlo[MT * 256];   // 32 KB  (total 64 KB -> 2 blocks/CU)

    const int tid = threadIdx.x;
    const int m0 = blockIdx.x * MT;

    const int wv   = tid >> 6;
    const int wvf  = wv & 3;       // feature group: cols [64*wvf, 64*wvf+64)
    const int ph   = wv >> 2;      // point half:    rows [32*ph, 32*ph+32)
    const int lane = tid & 63;
    const int quad = lane >> 4;
    const int l16  = lane & 15;

    // issue first wh loads NOW -- stays in flight across the lgkm-only barrier
    short8 cwh[4];
    LOADWH(cwh, 0, 0);

    // ---- layer 1: 2 -> 256 (VALU) -> X. Thread owns 4 cols, 8 rounds. ----
    {
        const int nq = lane * 4;
        const float4v w0 = *(const float4v*)(W1 + nq);          // W1[0][nq..nq+3]
        const float4v w1 = *(const float4v*)(W1 + WIDTH + nq);  // W1[1][nq..nq+3]
        const float4v bb = *(const float4v*)(b1 + nq);
        #pragma unroll
        for (int i = 0; i < 8; ++i) {
            const int m = 8 * i + wv;
            const float c0 = coords[(m0 + m) * 2];       // wave-uniform address
            const float c1 = coords[(m0 + m) * 2 + 1];
            float v[4];
            #pragma unroll
            for (int j = 0; j < 4; ++j)
                v[j] = fmaxf(fmaf(c0, w0[j], fmaf(c1, w1[j], bb[j])), 0.0f);
            const int a = xaddr(m, nq);                  // nq&7 in {0,4}: stays in chunk
            *(uint2v*)(Xhi + a) = (uint2v){phi2(v[0], v[1]), phi2(v[2], v[3])};
            *(uint2v*)(Xlo + a) = (uint2v){plo2(v[0], v[1]), plo2(v[2], v[3])};
        }
    }
    barrier_lgkm();

    float sdot[2] = {0.f, 0.f};   // fused layer-6 partials (pt = 0,1)

    // ---- layers 2..5: 256 -> 256 via 16x16x32 bf16 MFMA, operand-swapped.
    //      Wave computes 64 features x 32 points: 4 LDS reads + 8 global/ks. ----
    #pragma unroll
    for (int l = 0; l < 4; ++l) {
        const float* bias = (l == 0) ? b2 : (l == 1) ? b3 : (l == 2) ? b4 : b5;

        float4v acc[4][2];   // acc[ft][pt] -- 32 VGPRs
        #pragma unroll
        for (int ft = 0; ft < 4; ++ft)
            #pragma unroll
            for (int pt = 0; pt < 2; ++pt)
                acc[ft][pt] = (float4v){0.f, 0.f, 0.f, 0.f};

        #pragma unroll
        for (int ks = 0; ks < 8; ++ks) {
            // prefetch next wh (next ks, or next layer's ks=0)
            short8 nwh[4];
            if (ks < 7) {
                LOADWH(nwh, l, ks + 1);
            } else if (l < 3) {
                LOADWH(nwh, l + 1, 0);
            }
            // wl JIT: first used at MFMA #17 (~310 cyc cover)
            short8 cwl[4];
            LOADWL(cwl, l, ks);
            // B-frags JIT from LDS: B[k][p], p = 32*ph + 16*pt + l16
            short8 xh[2], xl[2];
            #pragma unroll
            for (int pt = 0; pt < 2; ++pt) {
                const int off = xaddr(32 * ph + 16 * pt + l16, 32 * ks + 8 * quad);
                xh[pt] = *(const short8*)(Xhi + off);
                xl[pt] = *(const short8*)(Xlo + off);
            }
            __builtin_amdgcn_s_setprio(1);
            // product-major: dependent same-acc MFMAs 8 issue slots apart
            #pragma unroll
            for (int ft = 0; ft < 4; ++ft)
                #pragma unroll
                for (int pt = 0; pt < 2; ++pt)
                    acc[ft][pt] = __builtin_amdgcn_mfma_f32_16x16x32_bf16(cwh[ft], xh[pt], acc[ft][pt], 0, 0, 0);
            #pragma unroll
            for (int ft = 0; ft < 4; ++ft)
                #pragma unroll
                for (int pt = 0; pt < 2; ++pt)
                    acc[ft][pt] = __builtin_amdgcn_mfma_f32_16x16x32_bf16(cwh[ft], xl[pt], acc[ft][pt], 0, 0, 0);
            #pragma unroll
            for (int ft = 0; ft < 4; ++ft)
                #pragma unroll
                for (int pt = 0; pt < 2; ++pt)
                    acc[ft][pt] = __builtin_amdgcn_mfma_f32_16x16x32_bf16(cwl[ft], xh[pt], acc[ft][pt], 0, 0, 0);
            __builtin_amdgcn_s_setprio(0);
            // rotate (SSA renames under full unroll -- no real moves)
            cwh[0] = nwh[0]; cwh[1] = nwh[1]; cwh[2] = nwh[2]; cwh[3] = nwh[3];
        }

        if (l < 3) {
            // epilogue VALU hoist: bias+ReLU+perm-pack BEFORE the read-barrier.
            uint2v eh[4][2], el[4][2];
            #pragma unroll
            for (int ft = 0; ft < 4; ++ft) {
                const int nb = 64 * wvf + 16 * ft + 4 * quad;   // nb&7 in {0,4}
                const float4v bb = *(const float4v*)(bias + nb);
                #pragma unroll
                for (int pt = 0; pt < 2; ++pt) {
                    float v[4];
                    #pragma unroll
                    for (int r = 0; r < 4; ++r)
                        v[r] = fmaxf(acc[ft][pt][r] + bb[r], 0.0f);
                    eh[ft][pt] = (uint2v){phi2(v[0], v[1]), phi2(v[2], v[3])};
                    el[ft][pt] = (uint2v){plo2(v[0], v[1]), plo2(v[2], v[3])};
                }
            }
            barrier_lgkm();    // all waves done READING X before overwrite
            // only the 16 b64 stores live in the serial window
            #pragma unroll
            for (int ft = 0; ft < 4; ++ft) {
                const int nb = 64 * wvf + 16 * ft + 4 * quad;
                #pragma unroll
                for (int pt = 0; pt < 2; ++pt) {
                    const int m = 32 * ph + 16 * pt + l16;
                    const int a = xaddr(m, nb);
                    *(uint2v*)(Xhi + a) = eh[ft][pt];
                    *(uint2v*)(Xlo + a) = el[ft][pt];
                }
            }
            barrier_lgkm();    // writes visible before next layer's reads
        } else {
            // fused layer 6: bias5 + ReLU + dot W6 straight from acc (full f32)
            #pragma unroll
            for (int ft = 0; ft < 4; ++ft) {
                const int nb = 64 * wvf + 16 * ft + 4 * quad;
                const float4v bb = *(const float4v*)(bias + nb);   // b5
                const float4v w6 = *(const float4v*)(W6 + nb);
                #pragma unroll
                for (int pt = 0; pt < 2; ++pt)
                    #pragma unroll
                    for (int r = 0; r < 4; ++r) {
                        const float v = fmaxf(acc[ft][pt][r] + bb[r], 0.0f);
                        sdot[pt] = fmaf(v, w6[r], sdot[pt]);
                    }
            }
            barrier_lgkm();    // all waves done reading X before part-writes below
        }
    }

    // ---- layer-6 reduction: quad-shuffle, then cross-wave via 1 KB LDS ----
    // lane<16 holds point (ph,pt,l16)'s sum over this wave's 64 features.
    {
        float* part = (float*)Xhi;   // part[wvf][point]: 4 x 64 floats
        #pragma unroll
        for (int pt = 0; pt < 2; ++pt) {
            float s = sdot[pt];
            s += __shfl_xor(s, 16);
            s += __shfl_xor(s, 32);
            if (lane < 16) part[wvf * 64 + ph * 32 + pt * 16 + l16] = s;
        }
        barrier_lgkm();
        if (tid < 64) {
            float s = b6[0];
            #pragma unroll
            for (int w = 0; w < 4; ++w)
                s += part[w * 64 + tid];
            out[m0 + tid] = s;
        }
    }
}

extern "C" void kernel_launch(void* const* d_in, const int* in_sizes, int n_in,
                              void* d_out, int out_size, void* d_ws, size_t ws_size,
                              hipStream_t stream) {
    const float* coords = (const float*)d_in[0];
    const float* W1 = (const float*)d_in[1];
    const float* b1 = (const float*)d_in[2];
    const float* W2 = (const float*)d_in[3];
    const float* b2 = (const float*)d_in[4];
    const float* W3 = (const float*)d_in[5];
    const float* b3 = (const float*)d_in[6];
    const float* W4 = (const float*)d_in[7];
    const float* b4 = (const float*)d_in[8];
    const float* W5 = (const float*)d_in[9];
    const float* b5 = (const float*)d_in[10];
    const float* W6 = (const float*)d_in[11];
    const float* b6 = (const float*)d_in[12];
    float* out = (float*)d_out;

    unsigned short* whi = (unsigned short*)d_ws;        // 4*65536 ushorts = 512 KB
    unsigned short* wlo = whi + 4 * 65536;              // 512 KB (ws total 1 MB)

    prep_weights<<<1024, 256, 0, stream>>>(W2, W3, W4, W5, whi, wlo);

    const int nblocks = out_size / MT;                  // 524288 / 64 = 8192
    mlp_fused<<<nblocks, 512, 0, stream>>>(coords, W1, b1, b2, b3, b4, b5,
                                           W6, b6, whi, wlo, out);
}

// Round 14
// 737.292 us; speedup vs baseline: 1.0646x; 1.0646x over previous
//
#include <hip/hip_runtime.h>
#include <stdint.h>

// SmallMLP_INR: fused 6-layer MLP (2->256->256x4->1, ReLU) over 524288 points.
// Split-bf16 MFMA (x = hi + lo, truncate split): Y = Xh*Wh + Xh*Wl + Xl*Wh in fp32.
// Operand-swapped: Yt = Wt * Xt (weights = A-frag from global, acts = B-frag in LDS).
// R14 = R13's (4ft x 2pt) wave split with the register envelope fixed.
// R13 validated the mechanism (BANK_CONFLICT 7.97e7 -> 4.61e7: LDS port demand
// halves) but spilled: hoisted epilogue regs pushed the live set to ~127 vs the
// 128 cap of launch_bounds(512,4) -> allocator chose 64+scratch (R8 pattern).
// Fix: PLAIN post-barrier epilogue (R7 style; R12 proved hoist ~neutral).
// Static budget: cwh[4]16 + nwh[4]16 + cwl[4]16 + xh/xl 16 + acc 32 + addr ~15
// = ~111 < 128. Kept: wh-only 1-ks-ahead prefetch (wl JIT, first use at MFMA
// #17 = ~310 cyc cover), lgkm-only barriers, fused L6, setprio, 16x16x32, MT=64.

#define WIDTH 256
#define MT 64

typedef short short8 __attribute__((ext_vector_type(8)));
typedef float float4v __attribute__((ext_vector_type(4)));
typedef unsigned int uint2v __attribute__((ext_vector_type(2)));

// lgkm-only barrier: LDS ordering without draining global (vmcnt) prefetch.
__device__ __forceinline__ void barrier_lgkm() {
    asm volatile("s_waitcnt lgkmcnt(0)" ::: "memory");
    __builtin_amdgcn_s_barrier();
    __builtin_amdgcn_sched_barrier(0);
}

// truncate-split f32 -> bf16 hi + bf16 lo (lo also truncated; total ~16-17 bits)
__device__ __forceinline__ void split_bf(float f, unsigned short &hi, unsigned short &lo) {
    union { float f; uint32_t u; } a; a.f = f;
    hi = (unsigned short)(a.u >> 16);
    union { uint32_t u; float f; } h; h.u = a.u & 0xffff0000u;
    union { float f; uint32_t u; } d; d.f = f - h.f;   // exact (Sterbenz)
    lo = (unsigned short)(d.u >> 16);
}

// pack hi(bf16) of two f32 into one u32 via v_perm_b32: D = {a.b2,a.b3,b.b2,b.b3}
__device__ __forceinline__ uint32_t phi2(float a, float b) {
    return __builtin_amdgcn_perm(__float_as_uint(b), __float_as_uint(a), 0x07060302u);
}
// pack lo(bf16) of two f32: residual after hi-truncation, then perm-pack
__device__ __forceinline__ uint32_t plo2(float a, float b) {
    float da = a - __uint_as_float(__float_as_uint(a) & 0xffff0000u);
    float db = b - __uint_as_float(__float_as_uint(b) & 0xffff0000u);
    return __builtin_amdgcn_perm(__float_as_uint(db), __float_as_uint(da), 0x07060302u);
}

// LDS activation addressing: X[m][n], row stride 256 ushorts, 16B-chunk index
// XOR-swizzled by (m&7) -> bank-minimal MFMA B-frag reads without padding.
__device__ __forceinline__ int xaddr(int m, int n) {
    int c = n >> 3;
    return m * 256 + (((c ^ (m & 7)) << 3) | (n & 7));
}

// Pack W2..W5 (256x256, row-major [k][n]) into MFMA fragment order:
// [l][ct(16)][ks(8)][lane(64)][j(8)], n = 16*ct + (lane&15), k = 32*ks + 8*(lane>>4) + j.
__global__ void prep_weights(const float* __restrict__ W2, const float* __restrict__ W3,
                             const float* __restrict__ W4, const float* __restrict__ W5,
                             unsigned short* __restrict__ whi, unsigned short* __restrict__ wlo) {
    int tid = blockIdx.x * 256 + threadIdx.x;   // 4*65536 total
    int l = tid >> 16;
    int e = tid & 65535;
    int j = e & 7;
    int lane = (e >> 3) & 63;
    int ks = (e >> 9) & 7;
    int ct = (e >> 12) & 15;
    int n = ct * 16 + (lane & 15);
    int k = ks * 32 + (lane >> 4) * 8 + j;
    const float* W = (l == 0) ? W2 : (l == 1) ? W3 : (l == 2) ? W4 : W5;
    float w = W[k * 256 + n];
    unsigned short hi, lo;
    split_bf(w, hi, lo);
    whi[tid] = hi;
    wlo[tid] = lo;
}

// weight hi A-frag load: ct = 4*wvf + ft (wave owns 64 consecutive features)
#define LOADWH(WH, L, KS)                                                      \
    do {                                                                       \
        _Pragma("unroll")                                                      \
        for (int _ft = 0; _ft < 4; ++_ft) {                                    \
            const int _idx = ((((L) * 16) + (4 * wvf + _ft)) * 8 + (KS)) * 512 \
                             + lane * 8;                                       \
            WH[_ft] = *(const short8*)(whi + _idx);                            \
        }                                                                      \
    } while (0)

// weight lo A-frag load (JIT: first used at MFMA #17 of the burst)
#define LOADWL(WL, L, KS)                                                      \
    do {                                                                       \
        _Pragma("unroll")                                                      \
        for (int _ft = 0; _ft < 4; ++_ft) {                                    \
            const int _idx = ((((L) * 16) + (4 * wvf + _ft)) * 8 + (KS)) * 512 \
                             + lane * 8;                                       \
            WL[_ft] = *(const short8*)(wlo + _idx);                            \
        }                                                                      \
    } while (0)

__global__ __launch_bounds__(512, 4) void mlp_fused(
    const float* __restrict__ coords,
    const float* __restrict__ W1, const float* __restrict__ b1,
    const float* __restrict__ b2, const float* __restrict__ b3,
    const float* __restrict__ b4, const float* __restrict__ b5,
    const float* __restrict__ W6, const float* __restrict__ b6,
    const unsigned short* __restrict__ whi, const unsigned short* __restrict__ wlo,
    float* __restrict__ out)
{
    __shared__ unsigned short Xhi[MT * 256];   // 32 KB
    __shared__ unsigned short Xlo[MT * 256];   // 32 KB  (total 64 KB -> 2 blocks/CU)

    const int tid = threadIdx.x;
    const int m0 = blockIdx.x * MT;

    const int wv   = tid >> 6;
    const int wvf  = wv & 3;       // feature group: cols [64*wvf, 64*wvf+64)
    const int ph   = wv >> 2;      // point half:    rows [32*ph, 32*ph+32)
    const int lane = tid & 63;
    const int quad = lane >> 4;
    const int l16  = lane & 15;

    // issue first wh loads NOW -- stays in flight across the lgkm-only barrier
    short8 cwh[4];
    LOADWH(cwh, 0, 0);

    // ---- layer 1: 2 -> 256 (VALU) -> X. Thread owns 4 cols, 8 rounds. ----
    {
        const int nq = lane * 4;
        const float4v w0 = *(const float4v*)(W1 + nq);          // W1[0][nq..nq+3]
        const float4v w1 = *(const float4v*)(W1 + WIDTH + nq);  // W1[1][nq..nq+3]
        const float4v bb = *(const float4v*)(b1 + nq);
        #pragma unroll
        for (int i = 0; i < 8; ++i) {
            const int m = 8 * i + wv;
            const float c0 = coords[(m0 + m) * 2];       // wave-uniform address
            const float c1 = coords[(m0 + m) * 2 + 1];
            float v[4];
            #pragma unroll
            for (int j = 0; j < 4; ++j)
                v[j] = fmaxf(fmaf(c0, w0[j], fmaf(c1, w1[j], bb[j])), 0.0f);
            const int a = xaddr(m, nq);                  // nq&7 in {0,4}: stays in chunk
            *(uint2v*)(Xhi + a) = (uint2v){phi2(v[0], v[1]), phi2(v[2], v[3])};
            *(uint2v*)(Xlo + a) = (uint2v){plo2(v[0], v[1]), plo2(v[2], v[3])};
        }
    }
    barrier_lgkm();

    float sdot[2] = {0.f, 0.f};   // fused layer-6 partials (pt = 0,1)

    // ---- layers 2..5: 256 -> 256 via 16x16x32 bf16 MFMA, operand-swapped.
    //      Wave computes 64 features x 32 points: 4 LDS reads + 8 global/ks. ----
    #pragma unroll
    for (int l = 0; l < 4; ++l) {
        const float* bias = (l == 0) ? b2 : (l == 1) ? b3 : (l == 2) ? b4 : b5;

        float4v acc[4][2];   // acc[ft][pt] -- 32 VGPRs
        #pragma unroll
        for (int ft = 0; ft < 4; ++ft)
            #pragma unroll
            for (int pt = 0; pt < 2; ++pt)
                acc[ft][pt] = (float4v){0.f, 0.f, 0.f, 0.f};

        #pragma unroll
        for (int ks = 0; ks < 8; ++ks) {
            // prefetch next wh (next ks, or next layer's ks=0)
            short8 nwh[4];
            if (ks < 7) {
                LOADWH(nwh, l, ks + 1);
            } else if (l < 3) {
                LOADWH(nwh, l + 1, 0);
            }
            // wl JIT: first used at MFMA #17 (~310 cyc cover)
            short8 cwl[4];
            LOADWL(cwl, l, ks);
            // B-frags JIT from LDS: B[k][p], p = 32*ph + 16*pt + l16
            short8 xh[2], xl[2];
            #pragma unroll
            for (int pt = 0; pt < 2; ++pt) {
                const int off = xaddr(32 * ph + 16 * pt + l16, 32 * ks + 8 * quad);
                xh[pt] = *(const short8*)(Xhi + off);
                xl[pt] = *(const short8*)(Xlo + off);
            }
            __builtin_amdgcn_s_setprio(1);
            // product-major: dependent same-acc MFMAs 8 issue slots apart
            #pragma unroll
            for (int ft = 0; ft < 4; ++ft)
                #pragma unroll
                for (int pt = 0; pt < 2; ++pt)
                    acc[ft][pt] = __builtin_amdgcn_mfma_f32_16x16x32_bf16(cwh[ft], xh[pt], acc[ft][pt], 0, 0, 0);
            #pragma unroll
            for (int ft = 0; ft < 4; ++ft)
                #pragma unroll
                for (int pt = 0; pt < 2; ++pt)
                    acc[ft][pt] = __builtin_amdgcn_mfma_f32_16x16x32_bf16(cwh[ft], xl[pt], acc[ft][pt], 0, 0, 0);
            #pragma unroll
            for (int ft = 0; ft < 4; ++ft)
                #pragma unroll
                for (int pt = 0; pt < 2; ++pt)
                    acc[ft][pt] = __builtin_amdgcn_mfma_f32_16x16x32_bf16(cwl[ft], xh[pt], acc[ft][pt], 0, 0, 0);
            __builtin_amdgcn_s_setprio(0);
            // rotate (SSA renames under full unroll -- no real moves)
            cwh[0] = nwh[0]; cwh[1] = nwh[1]; cwh[2] = nwh[2]; cwh[3] = nwh[3];
        }
        barrier_lgkm();    // all waves done READING X before overwrite

        if (l < 3) {
            // plain epilogue (R7 style): bias+ReLU+perm-pack, b64 writes into X.
            #pragma unroll
            for (int ft = 0; ft < 4; ++ft) {
                const int nb = 64 * wvf + 16 * ft + 4 * quad;   // nb&7 in {0,4}
                const float4v bb = *(const float4v*)(bias + nb);
                #pragma unroll
                for (int pt = 0; pt < 2; ++pt) {
                    const int m = 32 * ph + 16 * pt + l16;
                    float v[4];
                    #pragma unroll
                    for (int r = 0; r < 4; ++r)
                        v[r] = fmaxf(acc[ft][pt][r] + bb[r], 0.0f);
                    const int a = xaddr(m, nb);
                    *(uint2v*)(Xhi + a) = (uint2v){phi2(v[0], v[1]), phi2(v[2], v[3])};
                    *(uint2v*)(Xlo + a) = (uint2v){plo2(v[0], v[1]), plo2(v[2], v[3])};
                }
            }
            barrier_lgkm();    // writes visible before next layer's reads
        } else {
            // fused layer 6: bias5 + ReLU + dot W6 straight from acc (full f32)
            #pragma unroll
            for (int ft = 0; ft < 4; ++ft) {
                const int nb = 64 * wvf + 16 * ft + 4 * quad;
                const float4v bb = *(const float4v*)(bias + nb);   // b5
                const float4v w6 = *(const float4v*)(W6 + nb);
                #pragma unroll
                for (int pt = 0; pt < 2; ++pt)
                    #pragma unroll
                    for (int r = 0; r < 4; ++r) {
                        const float v = fmaxf(acc[ft][pt][r] + bb[r], 0.0f);
                        sdot[pt] = fmaf(v, w6[r], sdot[pt]);
                    }
            }
        }
    }

    // ---- layer-6 reduction: quad-shuffle, then cross-wave via 1 KB LDS ----
    // lane<16 holds point (ph,pt,l16)'s sum over this wave's 64 features.
    {
        float* part = (float*)Xhi;   // part[wvf][point]: 4 x 64 floats
        #pragma unroll
        for (int pt = 0; pt < 2; ++pt) {
            float s = sdot[pt];
            s += __shfl_xor(s, 16);
            s += __shfl_xor(s, 32);
            if (lane < 16) part[wvf * 64 + ph * 32 + pt * 16 + l16] = s;
        }
        barrier_lgkm();
        if (tid < 64) {
            float s = b6[0];
            #pragma unroll
            for (int w = 0; w < 4; ++w)
                s += part[w * 64 + tid];
            out[m0 + tid] = s;
        }
    }
}

extern "C" void kernel_launch(void* const* d_in, const int* in_sizes, int n_in,
                              void* d_out, int out_size, void* d_ws, size_t ws_size,
                              hipStream_t stream) {
    const float* coords = (const float*)d_in[0];
    const float* W1 = (const float*)d_in[1];
    const float* b1 = (const float*)d_in[2];
    const float* W2 = (const float*)d_in[3];
    const float* b2 = (const float*)d_in[4];
    const float* W3 = (const float*)d_in[5];
    const float* b3 = (const float*)d_in[6];
    const float* W4 = (const float*)d_in[7];
    const float* b4 = (const float*)d_in[8];
    const float* W5 = (const float*)d_in[9];
    const float* b5 = (const float*)d_in[10];
    const float* W6 = (const float*)d_in[11];
    const float* b6 = (const float*)d_in[12];
    float* out = (float*)d_out;

    unsigned short* whi = (unsigned short*)d_ws;        // 4*65536 ushorts = 512 KB
    unsigned short* wlo = whi + 4 * 65536;              // 512 KB (ws total 1 MB)

    prep_weights<<<1024, 256, 0, stream>>>(W2, W3, W4, W5, whi, wlo);

    const int nblocks = out_size / MT;                  // 524288 / 64 = 8192
    mlp_fused<<<nblocks, 512, 0, stream>>>(coords, W1, b1, b2, b3, b4, b5,
                                           W6, b6, whi, wlo, out);
}

// Round 15
// 638.371 us; speedup vs baseline: 1.2295x; 1.1550x over previous
//
#include <hip/hip_runtime.h>
#include <stdint.h>

// SmallMLP_INR: fused 6-layer MLP (2->256->256x4->1, ReLU) over 524288 points.
// Split-bf16 MFMA (x = hi + lo, truncate split): Y = Xh*Wh + Xh*Wl + Xl*Wh in fp32.
// Operand-swapped: Yt = Wt * Xt (weights = A-frag from global, acts = B-frag in LDS).
// R15 = REVERT to R12 (best: 640.5 us, dispatch ~588, MfmaUtil ~71%).
// Final configuration. Ceiling arithmetic: 1536 MFMA/block x 19.4 cyc = 397 us
// floor; measured pipe-busy ~412 us (97% of ubench rate when fed). Residual
// ~175 us = inter-layer LDS round-trip serialization (width-256 all-to-all
// dependency, 2 blocks/CU at the 128 KB usable-LDS wall). All levers exhausted:
// shape (R2/R10), occupancy (R3/R8/R9), traffic (R4/R13/R14), reg pipelining
// (R5/R11), barrier relax + hoist (R12 neutral). (4ft,2pt) LDS-halving spills
// unavoidably (R13/R14). 2-product arithmetic breaks the 1.99e-4 threshold.

#define WIDTH 256
#define MT 64

typedef short short8 __attribute__((ext_vector_type(8)));
typedef float float4v __attribute__((ext_vector_type(4)));
typedef unsigned int uint2v __attribute__((ext_vector_type(2)));

// lgkm-only barrier: LDS ordering without draining global (vmcnt) prefetch.
__device__ __forceinline__ void barrier_lgkm() {
    asm volatile("s_waitcnt lgkmcnt(0)" ::: "memory");
    __builtin_amdgcn_s_barrier();
    __builtin_amdgcn_sched_barrier(0);
}

// truncate-split f32 -> bf16 hi + bf16 lo (lo also truncated; total ~16-17 bits)
__device__ __forceinline__ void split_bf(float f, unsigned short &hi, unsigned short &lo) {
    union { float f; uint32_t u; } a; a.f = f;
    hi = (unsigned short)(a.u >> 16);
    union { uint32_t u; float f; } h; h.u = a.u & 0xffff0000u;
    union { float f; uint32_t u; } d; d.f = f - h.f;   // exact (Sterbenz)
    lo = (unsigned short)(d.u >> 16);
}

// pack hi(bf16) of two f32 into one u32 via v_perm_b32: D = {a.b2,a.b3,b.b2,b.b3}
__device__ __forceinline__ uint32_t phi2(float a, float b) {
    return __builtin_amdgcn_perm(__float_as_uint(b), __float_as_uint(a), 0x07060302u);
}
// pack lo(bf16) of two f32: residual after hi-truncation, then perm-pack
__device__ __forceinline__ uint32_t plo2(float a, float b) {
    float da = a - __uint_as_float(__float_as_uint(a) & 0xffff0000u);
    float db = b - __uint_as_float(__float_as_uint(b) & 0xffff0000u);
    return __builtin_amdgcn_perm(__float_as_uint(db), __float_as_uint(da), 0x07060302u);
}

// LDS activation addressing: X[m][n], row stride 256 ushorts, 16B-chunk index
// XOR-swizzled by (m&7) -> bank-minimal MFMA B-frag reads without padding.
__device__ __forceinline__ int xaddr(int m, int n) {
    int c = n >> 3;
    return m * 256 + (((c ^ (m & 7)) << 3) | (n & 7));
}

// Pack W2..W5 (256x256, row-major [k][n]) into MFMA fragment order:
// [l][ct(16)][ks(8)][lane(64)][j(8)], n = 16*ct + (lane&15), k = 32*ks + 8*(lane>>4) + j.
__global__ void prep_weights(const float* __restrict__ W2, const float* __restrict__ W3,
                             const float* __restrict__ W4, const float* __restrict__ W5,
                             unsigned short* __restrict__ whi, unsigned short* __restrict__ wlo) {
    int tid = blockIdx.x * 256 + threadIdx.x;   // 4*65536 total
    int l = tid >> 16;
    int e = tid & 65535;
    int j = e & 7;
    int lane = (e >> 3) & 63;
    int ks = (e >> 9) & 7;
    int ct = (e >> 12) & 15;
    int n = ct * 16 + (lane & 15);
    int k = ks * 32 + (lane >> 4) * 8 + j;
    const float* W = (l == 0) ? W2 : (l == 1) ? W3 : (l == 2) ? W4 : W5;
    float w = W[k * 256 + n];
    unsigned short hi, lo;
    split_bf(w, hi, lo);
    whi[tid] = hi;
    wlo[tid] = lo;
}

// weight A-frag load: ct = 2*wv + ft (wave owns 32 consecutive features)
#define LOADW(WH, WL, L, KS)                                                   \
    do {                                                                       \
        _Pragma("unroll")                                                      \
        for (int _ft = 0; _ft < 2; ++_ft) {                                    \
            const int _idx = ((((L) * 16) + (2 * wv + _ft)) * 8 + (KS)) * 512  \
                             + lane * 8;                                       \
            WH[_ft] = *(const short8*)(whi + _idx);                            \
            WL[_ft] = *(const short8*)(wlo + _idx);                            \
        }                                                                      \
    } while (0)

__global__ __launch_bounds__(512, 4) void mlp_fused(
    const float* __restrict__ coords,
    const float* __restrict__ W1, const float* __restrict__ b1,
    const float* __restrict__ b2, const float* __restrict__ b3,
    const float* __restrict__ b4, const float* __restrict__ b5,
    const float* __restrict__ W6, const float* __restrict__ b6,
    const unsigned short* __restrict__ whi, const unsigned short* __restrict__ wlo,
    float* __restrict__ out)
{
    __shared__ unsigned short Xhi[MT * 256];   // 32 KB
    __shared__ unsigned short Xlo[MT * 256];   // 32 KB  (total 64 KB -> 2 blocks/CU)

    const int tid = threadIdx.x;
    const int m0 = blockIdx.x * MT;

    const int wv   = tid >> 6;     // wave 0..7 owns output features [32*wv, 32*wv+32)
    const int lane = tid & 63;
    const int quad = lane >> 4;
    const int l16  = lane & 15;

    // issue first weight loads NOW -- stays in flight across the lgkm-only barrier
    short8 cwh[2], cwl[2];
    LOADW(cwh, cwl, 0, 0);

    // ---- layer 1: 2 -> 256 (VALU) -> X. Thread owns 4 cols, 8 rounds. ----
    {
        const int nq = lane * 4;
        const float4v w0 = *(const float4v*)(W1 + nq);          // W1[0][nq..nq+3]
        const float4v w1 = *(const float4v*)(W1 + WIDTH + nq);  // W1[1][nq..nq+3]
        const float4v bb = *(const float4v*)(b1 + nq);
        #pragma unroll
        for (int i = 0; i < 8; ++i) {
            const int m = 8 * i + wv;
            const float c0 = coords[(m0 + m) * 2];       // wave-uniform address
            const float c1 = coords[(m0 + m) * 2 + 1];
            float v[4];
            #pragma unroll
            for (int j = 0; j < 4; ++j)
                v[j] = fmaxf(fmaf(c0, w0[j], fmaf(c1, w1[j], bb[j])), 0.0f);
            const int a = xaddr(m, nq);                  // nq&7 in {0,4}: stays in chunk
            *(uint2v*)(Xhi + a) = (uint2v){phi2(v[0], v[1]), phi2(v[2], v[3])};
            *(uint2v*)(Xlo + a) = (uint2v){plo2(v[0], v[1]), plo2(v[2], v[3])};
        }
    }
    barrier_lgkm();

    float sdot[4] = {0.f, 0.f, 0.f, 0.f};   // fused layer-6 partials

    // ---- layers 2..5: 256 -> 256 via 16x16x32 bf16 MFMA, operand-swapped.
    //      Single X buffer: lgkm-barrier after reads, lgkm-barrier after writes. ----
    #pragma unroll
    for (int l = 0; l < 4; ++l) {
        const float* bias = (l == 0) ? b2 : (l == 1) ? b3 : (l == 2) ? b4 : b5;

        float4v acc[2][4];   // acc[ft][pt] -- 32 VGPRs
        #pragma unroll
        for (int ft = 0; ft < 2; ++ft)
            #pragma unroll
            for (int pt = 0; pt < 4; ++pt)
                acc[ft][pt] = (float4v){0.f, 0.f, 0.f, 0.f};

        #pragma unroll
        for (int ks = 0; ks < 8; ++ks) {
            // prefetch next weights (next ks, or next layer's ks=0)
            short8 nwh[2], nwl[2];
            if (ks < 7) {
                LOADW(nwh, nwl, l, ks + 1);
            } else if (l < 3) {
                LOADW(nwh, nwl, l + 1, 0);
            }
            // B-frags just-in-time from LDS: B[k][p], p = l16, k = 32*ks+8*quad+j
            short8 xh[4], xl[4];
            #pragma unroll
            for (int pt = 0; pt < 4; ++pt) {
                const int off = xaddr(16 * pt + l16, 32 * ks + 8 * quad);
                xh[pt] = *(const short8*)(Xhi + off);
                xl[pt] = *(const short8*)(Xlo + off);
            }
            __builtin_amdgcn_s_setprio(1);
            // product-major: dependent same-acc MFMAs 8 issue slots apart
            #pragma unroll
            for (int ft = 0; ft < 2; ++ft)
                #pragma unroll
                for (int pt = 0; pt < 4; ++pt)
                    acc[ft][pt] = __builtin_amdgcn_mfma_f32_16x16x32_bf16(cwh[ft], xh[pt], acc[ft][pt], 0, 0, 0);
            #pragma unroll
            for (int ft = 0; ft < 2; ++ft)
                #pragma unroll
                for (int pt = 0; pt < 4; ++pt)
                    acc[ft][pt] = __builtin_amdgcn_mfma_f32_16x16x32_bf16(cwh[ft], xl[pt], acc[ft][pt], 0, 0, 0);
            #pragma unroll
            for (int ft = 0; ft < 2; ++ft)
                #pragma unroll
                for (int pt = 0; pt < 4; ++pt)
                    acc[ft][pt] = __builtin_amdgcn_mfma_f32_16x16x32_bf16(cwl[ft], xh[pt], acc[ft][pt], 0, 0, 0);
            __builtin_amdgcn_s_setprio(0);
            // rotate (SSA renames under full unroll -- no real moves)
            cwh[0] = nwh[0]; cwh[1] = nwh[1];
            cwl[0] = nwl[0]; cwl[1] = nwl[1];
        }

        if (l < 3) {
            // epilogue VALU hoist: bias+ReLU+perm-pack into named packed regs
            // BEFORE the read-barrier (no LDS ops here). acc dies -> net VGPR ~0.
            uint2v eh[2][4], el[2][4];
            #pragma unroll
            for (int ft = 0; ft < 2; ++ft) {
                const int nb = 32 * wv + 16 * ft + 4 * quad;   // nb&7 in {0,4}
                const float4v bb = *(const float4v*)(bias + nb);
                #pragma unroll
                for (int pt = 0; pt < 4; ++pt) {
                    float v[4];
                    #pragma unroll
                    for (int r = 0; r < 4; ++r)
                        v[r] = fmaxf(acc[ft][pt][r] + bb[r], 0.0f);
                    eh[ft][pt] = (uint2v){phi2(v[0], v[1]), phi2(v[2], v[3])};
                    el[ft][pt] = (uint2v){plo2(v[0], v[1]), plo2(v[2], v[3])};
                }
            }
            barrier_lgkm();    // all waves done READING X before overwrite
            // only the 16 b64 stores live in the serial window
            #pragma unroll
            for (int ft = 0; ft < 2; ++ft) {
                const int nb = 32 * wv + 16 * ft + 4 * quad;
                #pragma unroll
                for (int pt = 0; pt < 4; ++pt) {
                    const int m = 16 * pt + l16;
                    const int a = xaddr(m, nb);
                    *(uint2v*)(Xhi + a) = eh[ft][pt];
                    *(uint2v*)(Xlo + a) = el[ft][pt];
                }
            }
            barrier_lgkm();    // writes visible before next layer's reads
        } else {
            // fused layer 6: bias5 + ReLU + dot W6 straight from acc (full f32)
            #pragma unroll
            for (int ft = 0; ft < 2; ++ft) {
                const int nb = 32 * wv + 16 * ft + 4 * quad;
                const float4v bb = *(const float4v*)(bias + nb);   // b5
                const float4v w6 = *(const float4v*)(W6 + nb);
                #pragma unroll
                for (int pt = 0; pt < 4; ++pt)
                    #pragma unroll
                    for (int r = 0; r < 4; ++r) {
                        const float v = fmaxf(acc[ft][pt][r] + bb[r], 0.0f);
                        sdot[pt] = fmaf(v, w6[r], sdot[pt]);
                    }
            }
            barrier_lgkm();    // all waves done reading X before part-writes below
        }
    }

    // ---- layer-6 reduction: quad-shuffle, then cross-wave via 2 KB LDS ----
    {
        float* part = (float*)Xhi;
        #pragma unroll
        for (int pt = 0; pt < 4; ++pt) {
            float s = sdot[pt];
            s += __shfl_xor(s, 16);
            s += __shfl_xor(s, 32);
            if (lane < 16) part[wv * 64 + pt * 16 + l16] = s;
        }
        barrier_lgkm();
        if (tid < 64) {
            float s = b6[0];
            #pragma unroll
            for (int w = 0; w < 8; ++w)
                s += part[w * 64 + tid];
            out[m0 + tid] = s;
        }
    }
}

extern "C" void kernel_launch(void* const* d_in, const int* in_sizes, int n_in,
                              void* d_out, int out_size, void* d_ws, size_t ws_size,
                              hipStream_t stream) {
    const float* coords = (const float*)d_in[0];
    const float* W1 = (const float*)d_in[1];
    const float* b1 = (const float*)d_in[2];
    const float* W2 = (const float*)d_in[3];
    const float* b2 = (const float*)d_in[4];
    const float* W3 = (const float*)d_in[5];
    const float* b3 = (const float*)d_in[6];
    const float* W4 = (const float*)d_in[7];
    const float* b4 = (const float*)d_in[8];
    const float* W5 = (const float*)d_in[9];
    const float* b5 = (const float*)d_in[10];
    const float* W6 = (const float*)d_in[11];
    const float* b6 = (const float*)d_in[12];
    float* out = (float*)d_out;

    unsigned short* whi = (unsigned short*)d_ws;        // 4*65536 ushorts = 512 KB
    unsigned short* wlo = whi + 4 * 65536;              // 512 KB (ws total 1 MB)

    prep_weights<<<1024, 256, 0, stream>>>(W2, W3, W4, W5, whi, wlo);

    const int nblocks = out_size / MT;                  // 524288 / 64 = 8192
    mlp_fused<<<nblocks, 512, 0, stream>>>(coords, W1, b1, b2, b3, b4, b5,
                                           W6, b6, whi, wlo, out);
}